// Round 11
// baseline (364.684 us; speedup 1.0000x reference)
//
#include <hip/hip_runtime.h>
#include <math.h>

#define DIMM 256
#define HEADS 8
#define NB 2048
#define BB 2
#define ROWS (BB*NB)   // 4096

typedef __attribute__((ext_vector_type(8))) short bf16x8;
typedef __attribute__((ext_vector_type(4))) short bf16x4;
typedef __attribute__((ext_vector_type(4))) float f32x4;

__device__ inline unsigned short f2bf(float f) {
    unsigned int u = __float_as_uint(f);
    u += 0x7FFFu + ((u >> 16) & 1u);           // RNE
    return (unsigned short)(u >> 16);
}
__device__ inline float bf2f(unsigned short u) {
    return __uint_as_float(((unsigned int)u) << 16);
}

__device__ inline int get_mask(const void* nm, int fmt, int idx) {
    if (fmt) return ((const unsigned char*)nm)[idx] != 0;
    return ((const int*)nm)[idx] != 0;
}

// ---------------- LayerNorm body, bf16 out ----------------
__device__ inline void ln8_body(const float* __restrict__ x, const float* __restrict__ g,
                                const float* __restrict__ bb, unsigned short* __restrict__ o,
                                int row, int lane32) {
    int c0 = lane32 * 8;
    float4 v0 = *(const float4*)&x[(size_t)row * DIMM + c0];
    float4 v1 = *(const float4*)&x[(size_t)row * DIMM + c0 + 4];
    float s  = v0.x + v0.y + v0.z + v0.w + v1.x + v1.y + v1.z + v1.w;
    float s2 = v0.x*v0.x + v0.y*v0.y + v0.z*v0.z + v0.w*v0.w
             + v1.x*v1.x + v1.y*v1.y + v1.z*v1.z + v1.w*v1.w;
#pragma unroll
    for (int off = 16; off >= 1; off >>= 1) {
        s  += __shfl_xor(s,  off);
        s2 += __shfl_xor(s2, off);
    }
    float mean = s * (1.0f / DIMM);
    float var  = s2 * (1.0f / DIMM) - mean * mean;
    float rstd = rsqrtf(var + 1e-5f);
    float4 g0 = *(const float4*)&g[c0],  g1 = *(const float4*)&g[c0 + 4];
    float4 b0 = *(const float4*)&bb[c0], b1 = *(const float4*)&bb[c0 + 4];
    ushort4 u0, u1;
    u0.x = f2bf((v0.x - mean) * rstd * g0.x + b0.x);
    u0.y = f2bf((v0.y - mean) * rstd * g0.y + b0.y);
    u0.z = f2bf((v0.z - mean) * rstd * g0.z + b0.z);
    u0.w = f2bf((v0.w - mean) * rstd * g0.w + b0.w);
    u1.x = f2bf((v1.x - mean) * rstd * g1.x + b1.x);
    u1.y = f2bf((v1.y - mean) * rstd * g1.y + b1.y);
    u1.z = f2bf((v1.z - mean) * rstd * g1.z + b1.z);
    u1.w = f2bf((v1.w - mean) * rstd * g1.w + b1.w);
    *(ushort4*)&o[(size_t)row * DIMM + c0]     = u0;
    *(ushort4*)&o[(size_t)row * DIMM + c0 + 4] = u1;
}

// ---------------- prep: w2bfT (0..191) + LN1 (192..703) + emaskP (704..2751) ----------
// emaskP: per (b, qt16, kt) unit of 512B. Lane L holds int2 at L*8:
// code nibble for [q = qt16*16 + (L&15)][key = kt*64 + t16*16 + (L>>4)*4 + r]
// lives in dword (t16>>1), bits ((t16&1)*16 + r*4).
__global__ __launch_bounds__(256) void prep_kernel(
    const float* __restrict__ w0, const float* __restrict__ w1,
    const float* __restrict__ w2, const float* __restrict__ w3,
    unsigned short* __restrict__ o0, unsigned short* __restrict__ o1,
    unsigned short* __restrict__ o2, unsigned short* __restrict__ o3,
    const float* __restrict__ x, const float* __restrict__ ln1_g,
    const float* __restrict__ ln1_b, unsigned short* __restrict__ h_ln,
    const int* __restrict__ etypes, const void* __restrict__ nmask,
    unsigned char* __restrict__ emaskP)
{
    __shared__ float tile[64][65];
    __shared__ int fsh;
    int bid = blockIdx.x, t = threadIdx.x;
    if (bid < 192) {
        const float* src; unsigned short* dst; int K, N, idx;
        if (bid < 48)       { src = w0; dst = o0; K = 256;  N = 768;  idx = bid; }
        else if (bid < 64)  { src = w1; dst = o1; K = 256;  N = 256;  idx = bid - 48; }
        else if (bid < 128) { src = w2; dst = o2; K = 256;  N = 1024; idx = bid - 64; }
        else                { src = w3; dst = o3; K = 1024; N = 256;  idx = bid - 128; }
        int ntiles = N >> 6;
        int k0 = (idx / ntiles) * 64, n0 = (idx % ntiles) * 64;
        int r = t >> 4, c4 = (t & 15) * 4;
#pragma unroll
        for (int i = 0; i < 4; ++i) {
            float4 v = *(const float4*)&src[(size_t)(k0 + r + i * 16) * N + n0 + c4];
            tile[r + i * 16][c4 + 0] = v.x;
            tile[r + i * 16][c4 + 1] = v.y;
            tile[r + i * 16][c4 + 2] = v.z;
            tile[r + i * 16][c4 + 3] = v.w;
        }
        __syncthreads();
#pragma unroll
        for (int i = 0; i < 4; ++i) {
            int n = n0 + r + i * 16;
            ushort4 u;
            u.x = f2bf(tile[c4 + 0][r + i * 16]);
            u.y = f2bf(tile[c4 + 1][r + i * 16]);
            u.z = f2bf(tile[c4 + 2][r + i * 16]);
            u.w = f2bf(tile[c4 + 3][r + i * 16]);
            *(ushort4*)&dst[(size_t)n * K + k0 + c4] = u;
        }
    } else if (bid < 704) {
        int row = (bid - 192) * 8 + (t >> 5);
        ln8_body(x, ln1_g, ln1_b, h_ln, row, t & 31);
    } else {
        if (t == 0) fsh = 0;
        __syncthreads();
        if (((const unsigned char*)nmask)[4 * t + 1] != 0) fsh = 1;
        __syncthreads();
        int fm = fsh;
        int unit = (bid - 704) * 4 + (t >> 6);
        int lane = t & 63, quad = lane >> 4, l15 = lane & 15;
        int b = unit >> 12;                 // 4096 units per batch
        int qt16 = (unit >> 5) & 127;
        int kt = unit & 31;
        int qr = qt16 * 16 + l15;
        int rowv = get_mask(nmask, fm, b * NB + qr);
        const int* erow = etypes + (size_t)(b * NB + qr) * NB;
        unsigned int dw[2] = {0u, 0u};
#pragma unroll
        for (int t16 = 0; t16 < 4; ++t16) {
            int col0 = kt * 64 + t16 * 16 + quad * 4;
            int4 e4 = *(const int4*)(erow + col0);
            int ee[4] = {e4.x, e4.y, e4.z, e4.w};
            int cv[4];
            if (fm) {
                unsigned int m4 = *(const unsigned int*)((const unsigned char*)nmask + b * NB + col0);
                cv[0] = (m4 & 0xffu) != 0;     cv[1] = (m4 & 0xff00u) != 0;
                cv[2] = (m4 & 0xff0000u) != 0; cv[3] = (m4 >> 24) != 0;
            } else {
                int4 m4 = *(const int4*)((const int*)nmask + b * NB + col0);
                cv[0] = m4.x != 0; cv[1] = m4.y != 0; cv[2] = m4.z != 0; cv[3] = m4.w != 0;
            }
#pragma unroll
            for (int r = 0; r < 4; ++r) {
                int col = col0 + r;
                int valid = rowv && cv[r] && ((ee[r] != 0) || (col == qr));
                unsigned int code = valid ? (unsigned int)(ee[r] + 1) : 0u;
                dw[t16 >> 1] |= code << ((t16 & 1) * 16 + r * 4);
            }
        }
        int2 o = {(int)dw[0], (int)dw[1]};
        *(int2*)(emaskP + (size_t)unit * 512 + lane * 8) = o;
    }
}

// ---------------- MFMA qkv GEMM (64x64); q columns pre-scaled by 1/sqrt(d) ----------
__global__ __launch_bounds__(256) void gemm_qkv_mfma(
    const unsigned short* __restrict__ A, const unsigned short* __restrict__ Bt,
    const float* __restrict__ bias,
    unsigned short* __restrict__ qkvh, unsigned short* __restrict__ vT)
{
    const int K = 256;
    int t = threadIdx.x, w = t >> 6, l = t & 63;
    int l15 = l & 15, quad = l >> 4;
    int n0 = blockIdx.x * 64;
    int m0 = blockIdx.y * 64;
    const unsigned short* ap = A + (size_t)(m0 + w * 16 + l15) * K + quad * 8;
    const unsigned short* bp = Bt + (size_t)(n0 + l15) * K + quad * 8;

    f32x4 acc[4];
#pragma unroll
    for (int c = 0; c < 4; ++c) acc[c] = (f32x4){0.f, 0.f, 0.f, 0.f};

    bf16x8 aA, bA[4], aB, bB[4];
    auto ld = [&](bf16x8& af, bf16x8 (&bf)[4], int k0) {
        af = *(const bf16x8*)(ap + k0);
#pragma unroll
        for (int c = 0; c < 4; ++c)
            bf[c] = *(const bf16x8*)(bp + (size_t)(c * 16) * K + k0);
    };
    auto pr = [&](const bf16x8& af, const bf16x8 (&bf)[4]) {
#pragma unroll
        for (int c = 0; c < 4; ++c)
            acc[c] = __builtin_amdgcn_mfma_f32_16x16x32_bf16(af, bf[c], acc[c], 0, 0, 0);
    };
    ld(aA, bA, 0);
    for (int k0 = 0; k0 < K; k0 += 64) {
        ld(aB, bB, k0 + 32);
        pr(aA, bA);
        if (k0 + 64 < K) ld(aA, bA, k0 + 64);
        pr(aB, bB);
    }

    if (n0 < 512) {
        float sc = (n0 < 256) ? 0.17677669529663689f : 1.0f;   // fold 1/sqrt(32) into q
#pragma unroll
        for (int r = 0; r < 4; ++r) {
            int row = m0 + w * 16 + quad * 4 + r;
#pragma unroll
            for (int c = 0; c < 4; ++c) {
                int col = n0 + c * 16 + l15;
                qkvh[(size_t)row * 512 + col] = f2bf((acc[c][r] + bias[col]) * sc);
            }
        }
    } else {
        int bb_ = m0 >> 11;
        int n = (m0 + w * 16 + quad * 4) & 2047;
#pragma unroll
        for (int c = 0; c < 4; ++c) {
            int col = n0 + c * 16 + l15 - 512;
            int hidx = col >> 5, d = col & 31;
            float bs = bias[n0 + c * 16 + l15];
            ushort4 u;
            u.x = f2bf(acc[c][0] + bs);
            u.y = f2bf(acc[c][1] + bs);
            u.z = f2bf(acc[c][2] + bs);
            u.w = f2bf(acc[c][3] + bs);
            *(ushort4*)&vT[(size_t)((bb_ * HEADS + hidx) * 32 + d) * NB + n] = u;
        }
    }
}

// ---------------- MFMA attention: S^T scores + b64 P stage + R6 PV, split-K=4 -------
// __launch_bounds__(256,8): pin VGPR<=64 (m69: waves/SIMD halve past 64; R9 ran
// this family spill-free at 60). 4-bit emask codes free exactly 4 VGPRs vs int4.
__global__ __launch_bounds__(256, 8) void attn_mfma(
    const unsigned short* __restrict__ qkvh,  // [4096][512] bf16: q(scaled)|k
    const unsigned short* __restrict__ vT,    // [512][2048] bf16
    const unsigned char* __restrict__ emaskP, // 4-bit permuted codes (see prep)
    const float* __restrict__ table,
    unsigned short* __restrict__ OpH, float* __restrict__ lpart)
{
    __shared__ unsigned short P[4][16][72];   // per-wave probs, row=q, col=key
    __shared__ float tab2m[16];               // exp(table) multipliers; [0]=0

    int t = threadIdx.x;
    int w = t >> 6, l = t & 63;
    int l15 = l & 15, quad = l >> 4;
    int h = blockIdx.x;                       // fastest -> id%8 == h (XCD pin)
    int qt = blockIdx.y;
    int z = blockIdx.z, b = z >> 2, sp = z & 3;
    int q0 = qt * 64 + w * 16;
    int kbase = sp * (NB / 4);

    if (t < 16) tab2m[t] = (t >= 1 && t < 10) ? __expf(table[(t - 1) * 8 + h]) : 0.f;
    __syncthreads();

    bf16x8 bq = *(const bf16x8*)(qkvh + (size_t)(b * NB + q0 + l15) * 512 + h * 32 + quad * 8);

    const unsigned short* kp = qkvh + (size_t)(b * NB + l15) * 512 + 256 + h * 32 + quad * 8;
    const unsigned short* vp = vT + (size_t)((b * HEADS + h) * 32 + l15) * NB + quad * 8;
    int qt16 = qt * 4 + w;
    const unsigned char* ep = emaskP + (size_t)((b * 128 + qt16) * 32) * 512 + l * 8;

    float lacc = 0.f;
    f32x4 O0 = {0.f, 0.f, 0.f, 0.f}, O1 = {0.f, 0.f, 0.f, 0.f};

    bf16x8 kA[4], kB[4];
    bf16x8 vA[2][2], vB[2][2];
    int2 eA, eB;

    auto loadtile = [&](bf16x8 (&kf)[4], bf16x8 (&vf)[2][2], int2& ef, int m0) {
#pragma unroll
        for (int t16 = 0; t16 < 4; ++t16)
            kf[t16] = *(const bf16x8*)(kp + (size_t)(m0 + t16 * 16) * 512);
#pragma unroll
        for (int ks = 0; ks < 2; ++ks) {
            vf[ks][0] = *(const bf16x8*)(vp + m0 + ks * 32);
            vf[ks][1] = *(const bf16x8*)(vp + 16 * NB + m0 + ks * 32);
        }
        ef = *(const int2*)(ep + (size_t)(m0 >> 6) * 512);
    };

    auto process = [&](const bf16x8 (&kf)[4], const bf16x8 (&vf)[2][2], const int2& ef) {
#pragma unroll
        for (int t16 = 0; t16 < 4; ++t16) {
            f32x4 zero = {0.f, 0.f, 0.f, 0.f};
            f32x4 sT = __builtin_amdgcn_mfma_f32_16x16x32_bf16(kf[t16], bq, zero, 0, 0, 0);
            unsigned int e = ((unsigned int)((t16 < 2) ? ef.x : ef.y)) >> ((t16 & 1) * 16);
            float p0 = __expf(sT[0]) * tab2m[e & 0xFu];
            float p1 = __expf(sT[1]) * tab2m[(e >> 4) & 0xFu];
            float p2 = __expf(sT[2]) * tab2m[(e >> 8) & 0xFu];
            float p3 = __expf(sT[3]) * tab2m[(e >> 12) & 0xFu];
            lacc += (p0 + p1) + (p2 + p3);
            bf16x4 pb;
            pb[0] = (short)f2bf(p0); pb[1] = (short)f2bf(p1);
            pb[2] = (short)f2bf(p2); pb[3] = (short)f2bf(p3);
            *(bf16x4*)&P[w][l15][t16 * 16 + quad * 4] = pb;   // one b64 write
        }
#pragma unroll
        for (int ks = 0; ks < 2; ++ks) {
            bf16x8 pa = *(const bf16x8*)&P[w][l15][ks * 32 + quad * 8];
            O0 = __builtin_amdgcn_mfma_f32_16x16x32_bf16(pa, vf[ks][0], O0, 0, 0, 0);
            O1 = __builtin_amdgcn_mfma_f32_16x16x32_bf16(pa, vf[ks][1], O1, 0, 0, 0);
        }
    };

    loadtile(kA, vA, eA, kbase);
    for (int m0 = kbase; m0 < kbase + NB / 4; m0 += 128) {
        loadtile(kB, vB, eB, m0 + 64);
        process(kA, vA, eA);
        if (m0 + 128 < kbase + NB / 4) loadtile(kA, vA, eA, m0 + 128);
        process(kB, vB, eB);
    }

    lacc += __shfl_xor(lacc, 16);
    lacc += __shfl_xor(lacc, 32);

    unsigned short* Ob = OpH + (size_t)sp * ROWS * DIMM;
#pragma unroll
    for (int r = 0; r < 4; ++r) {
        int row = b * NB + q0 + quad * 4 + r;
        Ob[(size_t)row * DIMM + h * 32 + l15]      = f2bf(O0[r]);
        Ob[(size_t)row * DIMM + h * 32 + 16 + l15] = f2bf(O1[r]);
    }
    if (quad == 0) {
        int row = b * NB + q0 + l15;
        lpart[(size_t)sp * ROWS * 8 + (size_t)row * 8 + h] = lacc;
    }
}

// ---------------- megaback: 8 rows/block (512 blocks -> 2 co-resident/CU) ------------
// A-rows duplicated via l15&7 (half MFMA rows wasted -- these GEMMs are latency-bound).
// ffn2 split into two 16-long accumulator chains. Register-lean weight buffering.
__global__ __launch_bounds__(1024, 8) void megaback(
    const unsigned short* __restrict__ OpH, const float* __restrict__ lpart,
    const unsigned short* __restrict__ projT, const float* __restrict__ proj_b,
    const float* __restrict__ x, const void* __restrict__ nmask,
    const float* __restrict__ g2, const float* __restrict__ b2,
    const unsigned short* __restrict__ f1T, const float* __restrict__ ffn_b1,
    const unsigned short* __restrict__ f2T, const float* __restrict__ ffn_b2,
    float* __restrict__ out)
{
    __shared__ float rinv_l[8][8];
    __shared__ float stats[8][2];
    __shared__ float redn[8][16][2];
    __shared__ unsigned short Astage[8][264];
    __shared__ float x1s[8][260];
    __shared__ unsigned short hstage[8][264];
    __shared__ unsigned short midstage[8][1032];
    __shared__ int fsh;

    int t = threadIdx.x;
    int w = t >> 6, l = t & 63;
    int l15 = l & 15, quad = l >> 4;
    int grow0 = blockIdx.x * 8;

    if (t == 0) fsh = 0;
    __syncthreads();
    if (((const unsigned char*)nmask)[4 * t + 1] != 0) fsh = 1;

    if (t < 64) {
        int row = t >> 3, h = t & 7;
        float s = 0.f;
#pragma unroll
        for (int sp = 0; sp < 4; ++sp)
            s += lpart[(size_t)sp * ROWS * 8 + (size_t)(grow0 + row) * 8 + h];
        rinv_l[row][h] = (s > 0.f) ? 1.f / s : 0.f;
    }
    __syncthreads();
    int fm = fsh;

    // combine OpH -> Astage (bf16): 512 threads cover 8 rows x 256 cols / 4
    if (t < 512) {
        int row = t >> 6, col4 = (t & 63) * 4;
        float rinv = rinv_l[row][col4 >> 5];
        float o0 = 0.f, o1 = 0.f, o2 = 0.f, o3 = 0.f;
#pragma unroll
        for (int sp = 0; sp < 4; ++sp) {
            ushort4 u = *(const ushort4*)&OpH[(size_t)sp * ROWS * DIMM +
                                             (size_t)(grow0 + row) * DIMM + col4];
            o0 += bf2f(u.x); o1 += bf2f(u.y); o2 += bf2f(u.z); o3 += bf2f(u.w);
        }
        ushort4 u;
        u.x = f2bf(o0 * rinv); u.y = f2bf(o1 * rinv);
        u.z = f2bf(o2 * rinv); u.w = f2bf(o3 * rinv);
        *(ushort4*)&Astage[row][col4] = u;
    }
    __syncthreads();

    // proj: wave w owns col = w*16+l15
    {
        int col = w * 16 + l15;
        f32x4 acc = (f32x4){0.f, 0.f, 0.f, 0.f};
        const unsigned short* bp = projT + (size_t)col * 256 + quad * 8;
        bf16x8 sb[4];
#pragma unroll
        for (int i = 0; i < 4; ++i) sb[i] = *(const bf16x8*)(bp + i * 32);
#pragma unroll
        for (int ch = 0; ch < 8; ++ch) {
            bf16x8 a = *(const bf16x8*)&Astage[l15 & 7][ch * 32 + quad * 8];
            acc = __builtin_amdgcn_mfma_f32_16x16x32_bf16(a, sb[ch & 3], acc, 0, 0, 0);
            if (ch + 4 < 8) sb[ch & 3] = *(const bf16x8*)(bp + (ch + 4) * 32);
        }
        float bs = proj_b[col];
#pragma unroll
        for (int r = 0; r < 4; ++r) {
            int row16 = quad * 4 + r;
            if (row16 < 8) {
                int grow = grow0 + row16;
                float mk = (float)get_mask(nmask, fm, grow);
                float v = (acc[r] + bs) * mk + x[(size_t)grow * DIMM + col];
                x1s[row16][col] = v;
                float s = v, s2 = v * v;
#pragma unroll
                for (int off = 1; off < 16; off <<= 1) {
                    s += __shfl_xor(s, off); s2 += __shfl_xor(s2, off);
                }
                if (l15 == 0) { redn[row16][w][0] = s; redn[row16][w][1] = s2; }
            }
        }
    }
    __syncthreads();
    if (t < 8) {
        float s = 0.f, s2 = 0.f;
#pragma unroll
        for (int ww = 0; ww < 16; ++ww) { s += redn[t][ww][0]; s2 += redn[t][ww][1]; }
        float mean = s * (1.f / DIMM);
        float var  = s2 * (1.f / DIMM) - mean * mean;
        stats[t][0] = mean; stats[t][1] = rsqrtf(var + 1e-5f);
    }
    __syncthreads();

    // LN2 -> hstage
    {
        int col = w * 16 + l15;
        float gv = g2[col], bv = b2[col];
#pragma unroll
        for (int r = 0; r < 4; ++r) {
            int row16 = quad * 4 + r;
            if (row16 < 8) {
                float hv = (x1s[row16][col] - stats[row16][0]) * stats[row16][1] * gv + bv;
                hstage[row16][col] = f2bf(hv);
            }
        }
    }
    __syncthreads();

    // ffn1 + tanh-gelu: wave w owns cols w*64..w*64+63 (single-buffered weights)
    {
        f32x4 acc[4];
#pragma unroll
        for (int c = 0; c < 4; ++c) acc[c] = (f32x4){0.f, 0.f, 0.f, 0.f};
        const unsigned short* bp = f1T + (size_t)(w * 64 + l15) * 256 + quad * 8;
#pragma unroll
        for (int ch = 0; ch < 8; ++ch) {
            bf16x8 a = *(const bf16x8*)&hstage[l15 & 7][ch * 32 + quad * 8];
#pragma unroll
            for (int c = 0; c < 4; ++c) {
                bf16x8 bw = *(const bf16x8*)(bp + (size_t)(c * 16) * 256 + ch * 32);
                acc[c] = __builtin_amdgcn_mfma_f32_16x16x32_bf16(a, bw, acc[c], 0, 0, 0);
            }
        }
#pragma unroll
        for (int c = 0; c < 4; ++c) {
            int col = w * 64 + c * 16 + l15;
            float bs = ffn_b1[col];
#pragma unroll
            for (int r = 0; r < 4; ++r) {
                int row16 = quad * 4 + r;
                if (row16 < 8) {
                    float v = acc[c][r] + bs;
                    float x2 = v * v;
                    float p = v * fmaf(0.07135481f, x2, 1.5957691f);
                    float e = __expf(p);
                    float gl = v * (e / (e + 1.f));
                    midstage[row16][col] = f2bf(gl);
                }
            }
        }
    }
    __syncthreads();

    // ffn2 + final residual: two independent 16-chains over K halves
    {
        int col = w * 16 + l15;
        f32x4 acc0 = (f32x4){0.f, 0.f, 0.f, 0.f};
        f32x4 acc1 = (f32x4){0.f, 0.f, 0.f, 0.f};
        const unsigned short* bp = f2T + (size_t)col * 1024 + quad * 8;
#pragma unroll
        for (int ch = 0; ch < 16; ++ch) {
            bf16x8 a0 = *(const bf16x8*)&midstage[l15 & 7][ch * 32 + quad * 8];
            bf16x8 w0 = *(const bf16x8*)(bp + ch * 32);
            acc0 = __builtin_amdgcn_mfma_f32_16x16x32_bf16(a0, w0, acc0, 0, 0, 0);
            bf16x8 a1 = *(const bf16x8*)&midstage[l15 & 7][(ch + 16) * 32 + quad * 8];
            bf16x8 w1 = *(const bf16x8*)(bp + (ch + 16) * 32);
            acc1 = __builtin_amdgcn_mfma_f32_16x16x32_bf16(a1, w1, acc1, 0, 0, 0);
        }
        f32x4 acc = acc0 + acc1;
        float bs = ffn_b2[col];
#pragma unroll
        for (int r = 0; r < 4; ++r) {
            int row16 = quad * 4 + r;
            if (row16 < 8) {
                int grow = grow0 + row16;
                float mk = (float)get_mask(nmask, fm, grow);
                out[(size_t)grow * DIMM + col] = x1s[row16][col] + (acc[r] + bs) * mk;
            }
        }
    }
}

// ---------------- launch ----------------
extern "C" void kernel_launch(void* const* d_in, const int* in_sizes, int n_in,
                              void* d_out, int out_size, void* d_ws, size_t ws_size,
                              hipStream_t stream) {
    const float* x       = (const float*)d_in[0];
    const int*   etypes  = (const int*)d_in[1];
    const void*  nmask   = d_in[2];
    const float* qkv_w   = (const float*)d_in[3];
    const float* qkv_b   = (const float*)d_in[4];
    const float* proj_w  = (const float*)d_in[5];
    const float* proj_b  = (const float*)d_in[6];
    const float* table   = (const float*)d_in[7];
    const float* ln1_g   = (const float*)d_in[8];
    const float* ln1_b   = (const float*)d_in[9];
    const float* ln2_g   = (const float*)d_in[10];
    const float* ln2_b   = (const float*)d_in[11];
    const float* ffn_w1  = (const float*)d_in[12];
    const float* ffn_b1  = (const float*)d_in[13];
    const float* ffn_w2  = (const float*)d_in[14];
    const float* ffn_b2  = (const float*)d_in[15];
    float* out = (float*)d_out;
    float* ws  = (float*)d_ws;

    float* lpart = ws;                               // 131,072 f (512 KB)
    unsigned short* ub = (unsigned short*)(ws + 131072);
    unsigned short* h_ln   = ub;                     // 1,048,576 us
    unsigned short* qkvh   = ub + 1048576;           // 2,097,152
    unsigned short* vT     = ub + 3145728;           // 1,048,576
    unsigned short* OpH    = ub + 4194304;           // 4,194,304 (4 splits)
    unsigned short* qkvT   = ub + 8388608;           // 196,608
    unsigned short* projT  = ub + 8585216;           // 65,536
    unsigned short* f1T    = ub + 8650752;           // 262,144
    unsigned short* f2T    = ub + 8912896;           // 262,144
    unsigned char* emaskP  = (unsigned char*)(ub + 9175040);  // 4,194,304 B

    prep_kernel<<<dim3(2752), dim3(256), 0, stream>>>(
        qkv_w, proj_w, ffn_w1, ffn_w2, qkvT, projT, f1T, f2T,
        x, ln1_g, ln1_b, h_ln, etypes, nmask, emaskP);
    gemm_qkv_mfma<<<dim3(12, 64), dim3(256), 0, stream>>>(h_ln, qkvT, qkv_b, qkvh, vT);
    attn_mfma<<<dim3(HEADS, NB/64, BB*4), dim3(256), 0, stream>>>(
        qkvh, vT, emaskP, table, OpH, lpart);
    megaback<<<dim3(ROWS/8), dim3(1024), 0, stream>>>(
        OpH, lpart, projT, proj_b, x, nmask, ln2_g, ln2_b,
        f1T, ffn_b1, f2T, ffn_b2, out);
}

// Round 12
// 219.671 us; speedup vs baseline: 1.6601x; 1.6601x over previous
//
#include <hip/hip_runtime.h>
#include <math.h>

#define DIMM 256
#define HEADS 8
#define NB 2048
#define BB 2
#define ROWS (BB*NB)   // 4096

typedef __attribute__((ext_vector_type(8))) short bf16x8;
typedef __attribute__((ext_vector_type(4))) short bf16x4;
typedef __attribute__((ext_vector_type(4))) float f32x4;

__device__ inline unsigned short f2bf(float f) {
    unsigned int u = __float_as_uint(f);
    u += 0x7FFFu + ((u >> 16) & 1u);           // RNE
    return (unsigned short)(u >> 16);
}
__device__ inline float bf2f(unsigned short u) {
    return __uint_as_float(((unsigned int)u) << 16);
}

__device__ inline int get_mask(const void* nm, int fmt, int idx) {
    if (fmt) return ((const unsigned char*)nm)[idx] != 0;
    return ((const int*)nm)[idx] != 0;
}

// ---------------- scan: valid-row list per batch + lpart zeroing for masked rows ------
__global__ __launch_bounds__(256) void scan_kernel(
    const void* __restrict__ nmask, int* __restrict__ nv,
    unsigned short* __restrict__ qidx, float* __restrict__ lpart)
{
    __shared__ int fsh;
    __shared__ int cnt[256];
    __shared__ int base[256];
    int b = blockIdx.x, t = threadIdx.x;
    if (t == 0) fsh = 0;
    __syncthreads();
    if (((const unsigned char*)nmask)[4 * t + 1] != 0) fsh = 1;
    __syncthreads();
    int fm = fsh;
    int m[8]; int c = 0;
#pragma unroll
    for (int i = 0; i < 8; ++i) {
        m[i] = get_mask(nmask, fm, b * NB + t * 8 + i);
        c += m[i];
    }
    cnt[t] = c;
    __syncthreads();
    if (t == 0) {
        int acc = 0;
        for (int i = 0; i < 256; ++i) { base[i] = acc; acc += cnt[i]; }
        nv[b] = acc;
    }
    __syncthreads();
    int off = base[t];
#pragma unroll
    for (int i = 0; i < 8; ++i) {
        int row = t * 8 + i;
        if (m[i]) {
            qidx[b * NB + off++] = (unsigned short)row;
        } else {
            // masked row: zero lpart so megaback's rinv guard sees lsum==0
#pragma unroll
            for (int sp = 0; sp < 4; ++sp) {
                float* lp = lpart + (size_t)sp * ROWS * 8 + (size_t)(b * NB + row) * 8;
                *(float4*)lp       = make_float4(0.f, 0.f, 0.f, 0.f);
                *(float4*)(lp + 4) = make_float4(0.f, 0.f, 0.f, 0.f);
            }
        }
    }
    __syncthreads();
    if (t == 0) {   // pad qidx to multiple of 16 with last valid row (safe dup reads)
        int n = nv[b];
        unsigned short last = (n > 0) ? qidx[b * NB + n - 1] : (unsigned short)0;
        int padend = (n + 15) & ~15;
        for (int i = n; i < padend; ++i) qidx[b * NB + i] = last;
    }
}

// ---------------- LayerNorm body, bf16 out ----------------
__device__ inline void ln8_body(const float* __restrict__ x, const float* __restrict__ g,
                                const float* __restrict__ bb, unsigned short* __restrict__ o,
                                int row, int lane32) {
    int c0 = lane32 * 8;
    float4 v0 = *(const float4*)&x[(size_t)row * DIMM + c0];
    float4 v1 = *(const float4*)&x[(size_t)row * DIMM + c0 + 4];
    float s  = v0.x + v0.y + v0.z + v0.w + v1.x + v1.y + v1.z + v1.w;
    float s2 = v0.x*v0.x + v0.y*v0.y + v0.z*v0.z + v0.w*v0.w
             + v1.x*v1.x + v1.y*v1.y + v1.z*v1.z + v1.w*v1.w;
#pragma unroll
    for (int off = 16; off >= 1; off >>= 1) {
        s  += __shfl_xor(s,  off);
        s2 += __shfl_xor(s2, off);
    }
    float mean = s * (1.0f / DIMM);
    float var  = s2 * (1.0f / DIMM) - mean * mean;
    float rstd = rsqrtf(var + 1e-5f);
    float4 g0 = *(const float4*)&g[c0],  g1 = *(const float4*)&g[c0 + 4];
    float4 b0 = *(const float4*)&bb[c0], b1 = *(const float4*)&bb[c0 + 4];
    ushort4 u0, u1;
    u0.x = f2bf((v0.x - mean) * rstd * g0.x + b0.x);
    u0.y = f2bf((v0.y - mean) * rstd * g0.y + b0.y);
    u0.z = f2bf((v0.z - mean) * rstd * g0.z + b0.z);
    u0.w = f2bf((v0.w - mean) * rstd * g0.w + b0.w);
    u1.x = f2bf((v1.x - mean) * rstd * g1.x + b1.x);
    u1.y = f2bf((v1.y - mean) * rstd * g1.y + b1.y);
    u1.z = f2bf((v1.z - mean) * rstd * g1.z + b1.z);
    u1.w = f2bf((v1.w - mean) * rstd * g1.w + b1.w);
    *(ushort4*)&o[(size_t)row * DIMM + c0]     = u0;
    *(ushort4*)&o[(size_t)row * DIMM + c0 + 4] = u1;
}

// ---------------- prep: w2bfT (0..191) + LN1 (192..703) + emaskP (704..2751) ----------
// emaskP (compact-q space): per (b, qt16, kt) unit of 512B. Lane L holds int2 at L*8:
// nibble for [q slot = qt16*16 + (L&15)][key = kt*64 + t16*16 + (L>>4)*4 + r]
// in dword (t16>>1), bits ((t16&1)*16 + r*4). Code 0 = invalid; else etype+1.
__global__ __launch_bounds__(256) void prep_kernel(
    const float* __restrict__ w0, const float* __restrict__ w1,
    const float* __restrict__ w2, const float* __restrict__ w3,
    unsigned short* __restrict__ o0, unsigned short* __restrict__ o1,
    unsigned short* __restrict__ o2, unsigned short* __restrict__ o3,
    const float* __restrict__ x, const float* __restrict__ ln1_g,
    const float* __restrict__ ln1_b, unsigned short* __restrict__ h_ln,
    const int* __restrict__ etypes, const void* __restrict__ nmask,
    unsigned char* __restrict__ emaskP,
    const int* __restrict__ nv, const unsigned short* __restrict__ qidx)
{
    __shared__ float tile[64][65];
    __shared__ int fsh;
    int bid = blockIdx.x, t = threadIdx.x;
    if (bid < 192) {
        const float* src; unsigned short* dst; int K, N, idx;
        if (bid < 48)       { src = w0; dst = o0; K = 256;  N = 768;  idx = bid; }
        else if (bid < 64)  { src = w1; dst = o1; K = 256;  N = 256;  idx = bid - 48; }
        else if (bid < 128) { src = w2; dst = o2; K = 256;  N = 1024; idx = bid - 64; }
        else                { src = w3; dst = o3; K = 1024; N = 256;  idx = bid - 128; }
        int ntiles = N >> 6;
        int k0 = (idx / ntiles) * 64, n0 = (idx % ntiles) * 64;
        int r = t >> 4, c4 = (t & 15) * 4;
#pragma unroll
        for (int i = 0; i < 4; ++i) {
            float4 v = *(const float4*)&src[(size_t)(k0 + r + i * 16) * N + n0 + c4];
            tile[r + i * 16][c4 + 0] = v.x;
            tile[r + i * 16][c4 + 1] = v.y;
            tile[r + i * 16][c4 + 2] = v.z;
            tile[r + i * 16][c4 + 3] = v.w;
        }
        __syncthreads();
#pragma unroll
        for (int i = 0; i < 4; ++i) {
            int n = n0 + r + i * 16;
            ushort4 u;
            u.x = f2bf(tile[c4 + 0][r + i * 16]);
            u.y = f2bf(tile[c4 + 1][r + i * 16]);
            u.z = f2bf(tile[c4 + 2][r + i * 16]);
            u.w = f2bf(tile[c4 + 3][r + i * 16]);
            *(ushort4*)&dst[(size_t)n * K + k0 + c4] = u;
        }
    } else if (bid < 704) {
        int row = (bid - 192) * 8 + (t >> 5);
        ln8_body(x, ln1_g, ln1_b, h_ln, row, t & 31);
    } else {
        if (t == 0) fsh = 0;
        __syncthreads();
        if (((const unsigned char*)nmask)[4 * t + 1] != 0) fsh = 1;
        __syncthreads();
        int fm = fsh;
        int unit = (bid - 704) * 4 + (t >> 6);
        int lane = t & 63, quad = lane >> 4, l15 = lane & 15;
        int b = unit >> 12;                 // 4096 units per batch
        int qt16 = (unit >> 5) & 127;
        int kt = unit & 31;
        int nvb = nv[b];
        if (qt16 * 16 >= nvb) return;       // unit never read by attn
        int slot = qt16 * 16 + l15;
        int validq = slot < nvb;
        int qr = qidx[b * NB + slot];       // padded to mult-16, safe
        const int* erow = etypes + (size_t)(b * NB + qr) * NB;
        unsigned int dw[2] = {0u, 0u};
#pragma unroll
        for (int t16 = 0; t16 < 4; ++t16) {
            int col0 = kt * 64 + t16 * 16 + quad * 4;
            int4 e4 = *(const int4*)(erow + col0);
            int ee[4] = {e4.x, e4.y, e4.z, e4.w};
            int cv[4];
            if (fm) {
                unsigned int m4 = *(const unsigned int*)((const unsigned char*)nmask + b * NB + col0);
                cv[0] = (m4 & 0xffu) != 0;     cv[1] = (m4 & 0xff00u) != 0;
                cv[2] = (m4 & 0xff0000u) != 0; cv[3] = (m4 >> 24) != 0;
            } else {
                int4 m4 = *(const int4*)((const int*)nmask + b * NB + col0);
                cv[0] = m4.x != 0; cv[1] = m4.y != 0; cv[2] = m4.z != 0; cv[3] = m4.w != 0;
            }
#pragma unroll
            for (int r = 0; r < 4; ++r) {
                int col = col0 + r;
                int valid = validq && cv[r] && ((ee[r] != 0) || (col == qr));
                unsigned int code = valid ? (unsigned int)(ee[r] + 1) : 0u;
                dw[t16 >> 1] |= code << ((t16 & 1) * 16 + r * 4);
            }
        }
        int2 o = {(int)dw[0], (int)dw[1]};
        *(int2*)(emaskP + (size_t)unit * 512 + lane * 8) = o;
    }
}

// ---------------- MFMA qkv GEMM (64x64); q columns pre-scaled by 1/sqrt(d) ----------
__global__ __launch_bounds__(256) void gemm_qkv_mfma(
    const unsigned short* __restrict__ A, const unsigned short* __restrict__ Bt,
    const float* __restrict__ bias,
    unsigned short* __restrict__ qkvh, unsigned short* __restrict__ vT)
{
    const int K = 256;
    int t = threadIdx.x, w = t >> 6, l = t & 63;
    int l15 = l & 15, quad = l >> 4;
    int n0 = blockIdx.x * 64;
    int m0 = blockIdx.y * 64;
    const unsigned short* ap = A + (size_t)(m0 + w * 16 + l15) * K + quad * 8;
    const unsigned short* bp = Bt + (size_t)(n0 + l15) * K + quad * 8;

    f32x4 acc[4];
#pragma unroll
    for (int c = 0; c < 4; ++c) acc[c] = (f32x4){0.f, 0.f, 0.f, 0.f};

    bf16x8 aA, bA[4], aB, bB[4];
    auto ld = [&](bf16x8& af, bf16x8 (&bf)[4], int k0) {
        af = *(const bf16x8*)(ap + k0);
#pragma unroll
        for (int c = 0; c < 4; ++c)
            bf[c] = *(const bf16x8*)(bp + (size_t)(c * 16) * K + k0);
    };
    auto pr = [&](const bf16x8& af, const bf16x8 (&bf)[4]) {
#pragma unroll
        for (int c = 0; c < 4; ++c)
            acc[c] = __builtin_amdgcn_mfma_f32_16x16x32_bf16(af, bf[c], acc[c], 0, 0, 0);
    };
    ld(aA, bA, 0);
    for (int k0 = 0; k0 < K; k0 += 64) {
        ld(aB, bB, k0 + 32);
        pr(aA, bA);
        if (k0 + 64 < K) ld(aA, bA, k0 + 64);
        pr(aB, bB);
    }

    if (n0 < 512) {
        float sc = (n0 < 256) ? 0.17677669529663689f : 1.0f;   // fold 1/sqrt(32) into q
#pragma unroll
        for (int r = 0; r < 4; ++r) {
            int row = m0 + w * 16 + quad * 4 + r;
#pragma unroll
            for (int c = 0; c < 4; ++c) {
                int col = n0 + c * 16 + l15;
                qkvh[(size_t)row * 512 + col] = f2bf((acc[c][r] + bias[col]) * sc);
            }
        }
    } else {
        int bb_ = m0 >> 11;
        int n = (m0 + w * 16 + quad * 4) & 2047;
#pragma unroll
        for (int c = 0; c < 4; ++c) {
            int col = n0 + c * 16 + l15 - 512;
            int hidx = col >> 5, d = col & 31;
            float bs = bias[n0 + c * 16 + l15];
            ushort4 u;
            u.x = f2bf(acc[c][0] + bs);
            u.y = f2bf(acc[c][1] + bs);
            u.z = f2bf(acc[c][2] + bs);
            u.w = f2bf(acc[c][3] + bs);
            *(ushort4*)&vT[(size_t)((bb_ * HEADS + hidx) * 32 + d) * NB + n] = u;
        }
    }
}

// ---------------- MFMA attention: compact-q, S^T scores + b64 P stage + R6 PV --------
// Waves whose compact q-tile is beyond nv[b] exit after the tab2m barrier.
__global__ __launch_bounds__(256) void attn_mfma(
    const unsigned short* __restrict__ qkvh,  // [4096][512] bf16: q(scaled)|k
    const unsigned short* __restrict__ vT,    // [512][2048] bf16
    const unsigned char* __restrict__ emaskP, // 4-bit compact-q codes (see prep)
    const float* __restrict__ table,
    const int* __restrict__ nv, const unsigned short* __restrict__ qidx,
    unsigned short* __restrict__ OpH, float* __restrict__ lpart)
{
    __shared__ unsigned short P[4][16][72];   // per-wave probs, row=q, col=key
    __shared__ float tab2m[16];               // exp(table) multipliers; [0]=0

    int t = threadIdx.x;
    int w = t >> 6, l = t & 63;
    int l15 = l & 15, quad = l >> 4;
    int h = blockIdx.x;                       // fastest -> id%8 == h (XCD pin)
    int qt = blockIdx.y;
    int z = blockIdx.z, b = z >> 2, sp = z & 3;
    int kbase = sp * (NB / 4);

    if (t < 16) tab2m[t] = (t >= 1 && t < 10) ? __expf(table[(t - 1) * 8 + h]) : 0.f;
    __syncthreads();                          // no barriers after this point

    int nvb = nv[b];
    int qt16 = qt * 4 + w;
    int q0c = qt16 * 16;
    if (q0c >= nvb) return;                   // compact-q skip: ~half the waves

    int qrow = b * NB + qidx[b * NB + q0c + l15];   // padded, safe
    bf16x8 bq = *(const bf16x8*)(qkvh + (size_t)qrow * 512 + h * 32 + quad * 8);

    const unsigned short* kp = qkvh + (size_t)(b * NB + l15) * 512 + 256 + h * 32 + quad * 8;
    const unsigned short* vp = vT + (size_t)((b * HEADS + h) * 32 + l15) * NB + quad * 8;
    const unsigned char* ep = emaskP + (size_t)((b * 128 + qt16) * 32) * 512 + l * 8;

    float lacc = 0.f;
    f32x4 O0 = {0.f, 0.f, 0.f, 0.f}, O1 = {0.f, 0.f, 0.f, 0.f};

    bf16x8 kA[4], kB[4];
    bf16x8 vA[2][2], vB[2][2];
    int2 eA, eB;

    auto loadtile = [&](bf16x8 (&kf)[4], bf16x8 (&vf)[2][2], int2& ef, int m0) {
#pragma unroll
        for (int t16 = 0; t16 < 4; ++t16)
            kf[t16] = *(const bf16x8*)(kp + (size_t)(m0 + t16 * 16) * 512);
#pragma unroll
        for (int ks = 0; ks < 2; ++ks) {
            vf[ks][0] = *(const bf16x8*)(vp + m0 + ks * 32);
            vf[ks][1] = *(const bf16x8*)(vp + 16 * NB + m0 + ks * 32);
        }
        ef = *(const int2*)(ep + (size_t)(m0 >> 6) * 512);
    };

    auto process = [&](const bf16x8 (&kf)[4], const bf16x8 (&vf)[2][2], const int2& ef) {
#pragma unroll
        for (int t16 = 0; t16 < 4; ++t16) {
            f32x4 zero = {0.f, 0.f, 0.f, 0.f};
            f32x4 sT = __builtin_amdgcn_mfma_f32_16x16x32_bf16(kf[t16], bq, zero, 0, 0, 0);
            unsigned int e = ((unsigned int)((t16 < 2) ? ef.x : ef.y)) >> ((t16 & 1) * 16);
            float p0 = __expf(sT[0]) * tab2m[e & 0xFu];
            float p1 = __expf(sT[1]) * tab2m[(e >> 4) & 0xFu];
            float p2 = __expf(sT[2]) * tab2m[(e >> 8) & 0xFu];
            float p3 = __expf(sT[3]) * tab2m[(e >> 12) & 0xFu];
            lacc += (p0 + p1) + (p2 + p3);
            bf16x4 pb;
            pb[0] = (short)f2bf(p0); pb[1] = (short)f2bf(p1);
            pb[2] = (short)f2bf(p2); pb[3] = (short)f2bf(p3);
            *(bf16x4*)&P[w][l15][t16 * 16 + quad * 4] = pb;   // one b64 write
        }
#pragma unroll
        for (int ks = 0; ks < 2; ++ks) {
            bf16x8 pa = *(const bf16x8*)&P[w][l15][ks * 32 + quad * 8];
            O0 = __builtin_amdgcn_mfma_f32_16x16x32_bf16(pa, vf[ks][0], O0, 0, 0, 0);
            O1 = __builtin_amdgcn_mfma_f32_16x16x32_bf16(pa, vf[ks][1], O1, 0, 0, 0);
        }
    };

    loadtile(kA, vA, eA, kbase);
    for (int m0 = kbase; m0 < kbase + NB / 4; m0 += 128) {
        loadtile(kB, vB, eB, m0 + 64);
        process(kA, vA, eA);
        if (m0 + 128 < kbase + NB / 4) loadtile(kA, vA, eA, m0 + 128);
        process(kB, vB, eB);
    }

    lacc += __shfl_xor(lacc, 16);
    lacc += __shfl_xor(lacc, 32);

    unsigned short* Ob = OpH + (size_t)sp * ROWS * DIMM;
#pragma unroll
    for (int r = 0; r < 4; ++r) {
        int slot = q0c + quad * 4 + r;
        if (slot < nvb) {
            int row = b * NB + qidx[b * NB + slot];
            Ob[(size_t)row * DIMM + h * 32 + l15]      = f2bf(O0[r]);
            Ob[(size_t)row * DIMM + h * 32 + 16 + l15] = f2bf(O1[r]);
        }
    }
    if (quad == 0 && q0c + l15 < nvb) {
        int row = b * NB + qidx[b * NB + q0c + l15];
        lpart[(size_t)sp * ROWS * 8 + (size_t)row * 8 + h] = lacc;
    }
}

// ---------------- megaback (R10 16-row version): combine+proj+LN2+ffn1+gelu+ffn2 ------
__global__ __launch_bounds__(1024) void megaback(
    const unsigned short* __restrict__ OpH, const float* __restrict__ lpart,
    const unsigned short* __restrict__ projT, const float* __restrict__ proj_b,
    const float* __restrict__ x, const void* __restrict__ nmask,
    const float* __restrict__ g2, const float* __restrict__ b2,
    const unsigned short* __restrict__ f1T, const float* __restrict__ ffn_b1,
    const unsigned short* __restrict__ f2T, const float* __restrict__ ffn_b2,
    float* __restrict__ out)
{
    __shared__ float rinv_l[16][8];
    __shared__ float stats[16][2];
    __shared__ float redn[16][16][2];
    __shared__ unsigned short Astage[16][264];
    __shared__ float x1s[16][260];
    __shared__ unsigned short hstage[16][264];
    __shared__ unsigned short midstage[16][1032];
    __shared__ int fsh;

    int t = threadIdx.x;
    int w = t >> 6, l = t & 63;
    int l15 = l & 15, quad = l >> 4;
    int grow0 = blockIdx.x * 16;

    if (t == 0) fsh = 0;
    __syncthreads();
    if (((const unsigned char*)nmask)[4 * t + 1] != 0) fsh = 1;

    if (t < 128) {
        int row = t >> 3, h = t & 7;
        float s = 0.f;
#pragma unroll
        for (int sp = 0; sp < 4; ++sp)
            s += lpart[(size_t)sp * ROWS * 8 + (size_t)(grow0 + row) * 8 + h];
        rinv_l[row][h] = (s > 0.f) ? 1.f / s : 0.f;
    }
    __syncthreads();
    int fm = fsh;

    {
        int row = t >> 6, col4 = (t & 63) * 4;
        float rinv = rinv_l[row][col4 >> 5];
        float o0 = 0.f, o1 = 0.f, o2 = 0.f, o3 = 0.f;
#pragma unroll
        for (int sp = 0; sp < 4; ++sp) {
            ushort4 u = *(const ushort4*)&OpH[(size_t)sp * ROWS * DIMM +
                                             (size_t)(grow0 + row) * DIMM + col4];
            o0 += bf2f(u.x); o1 += bf2f(u.y); o2 += bf2f(u.z); o3 += bf2f(u.w);
        }
        ushort4 u;
        u.x = f2bf(o0 * rinv); u.y = f2bf(o1 * rinv);
        u.z = f2bf(o2 * rinv); u.w = f2bf(o3 * rinv);
        *(ushort4*)&Astage[row][col4] = u;
    }
    __syncthreads();

    {
        int col = w * 16 + l15;
        f32x4 acc = (f32x4){0.f, 0.f, 0.f, 0.f};
        const unsigned short* bp = projT + (size_t)col * 256 + quad * 8;
        bf16x8 sb[4];
#pragma unroll
        for (int i = 0; i < 4; ++i) sb[i] = *(const bf16x8*)(bp + i * 32);
#pragma unroll
        for (int ch = 0; ch < 8; ++ch) {
            bf16x8 a = *(const bf16x8*)&Astage[l15][ch * 32 + quad * 8];
            acc = __builtin_amdgcn_mfma_f32_16x16x32_bf16(a, sb[ch & 3], acc, 0, 0, 0);
            if (ch + 4 < 8) sb[ch & 3] = *(const bf16x8*)(bp + (ch + 4) * 32);
        }
        float bs = proj_b[col];
#pragma unroll
        for (int r = 0; r < 4; ++r) {
            int row = quad * 4 + r, grow = grow0 + row;
            float mk = (float)get_mask(nmask, fm, grow);
            float v = (acc[r] + bs) * mk + x[(size_t)grow * DIMM + col];
            x1s[row][col] = v;
            float s = v, s2 = v * v;
#pragma unroll
            for (int off = 1; off < 16; off <<= 1) {
                s += __shfl_xor(s, off); s2 += __shfl_xor(s2, off);
            }
            if (l15 == 0) { redn[row][w][0] = s; redn[row][w][1] = s2; }
        }
    }
    __syncthreads();
    if (t < 16) {
        float s = 0.f, s2 = 0.f;
#pragma unroll
        for (int ww = 0; ww < 16; ++ww) { s += redn[t][ww][0]; s2 += redn[t][ww][1]; }
        float mean = s * (1.f / DIMM);
        float var  = s2 * (1.f / DIMM) - mean * mean;
        stats[t][0] = mean; stats[t][1] = rsqrtf(var + 1e-5f);
    }
    __syncthreads();

    {
        int col = w * 16 + l15;
        float gv = g2[col], bv = b2[col];
#pragma unroll
        for (int r = 0; r < 4; ++r) {
            int row = quad * 4 + r;
            float hv = (x1s[row][col] - stats[row][0]) * stats[row][1] * gv + bv;
            hstage[row][col] = f2bf(hv);
        }
    }
    __syncthreads();

    {
        f32x4 acc[4];
#pragma unroll
        for (int c = 0; c < 4; ++c) acc[c] = (f32x4){0.f, 0.f, 0.f, 0.f};
        const unsigned short* bp = f1T + (size_t)(w * 64 + l15) * 256 + quad * 8;
        bf16x8 bA[4], bB[4];
#pragma unroll
        for (int c = 0; c < 4; ++c) bA[c] = *(const bf16x8*)(bp + (size_t)(c * 16) * 256);
#pragma unroll
        for (int ch = 0; ch < 8; ++ch) {
            bf16x8 a = *(const bf16x8*)&hstage[l15][ch * 32 + quad * 8];
            if (ch + 1 < 8) {
#pragma unroll
                for (int c = 0; c < 4; ++c)
                    bB[c] = *(const bf16x8*)(bp + (size_t)(c * 16) * 256 + (ch + 1) * 32);
            }
#pragma unroll
            for (int c = 0; c < 4; ++c)
                acc[c] = __builtin_amdgcn_mfma_f32_16x16x32_bf16(a, bA[c], acc[c], 0, 0, 0);
#pragma unroll
            for (int c = 0; c < 4; ++c) bA[c] = bB[c];
        }
#pragma unroll
        for (int c = 0; c < 4; ++c) {
            int col = w * 64 + c * 16 + l15;
            float bs = ffn_b1[col];
#pragma unroll
            for (int r = 0; r < 4; ++r) {
                float v = acc[c][r] + bs;
                float x2 = v * v;
                float p = v * fmaf(0.07135481f, x2, 1.5957691f);
                float e = __expf(p);
                float gl = v * (e / (e + 1.f));
                midstage[quad * 4 + r][col] = f2bf(gl);
            }
        }
    }
    __syncthreads();

    {
        int col = w * 16 + l15;
        f32x4 acc = (f32x4){0.f, 0.f, 0.f, 0.f};
        const unsigned short* bp = f2T + (size_t)col * 1024 + quad * 8;
        bf16x8 sb[4];
#pragma unroll
        for (int i = 0; i < 4; ++i) sb[i] = *(const bf16x8*)(bp + i * 32);
#pragma unroll
        for (int ch = 0; ch < 32; ++ch) {
            bf16x8 a = *(const bf16x8*)&midstage[l15][ch * 32 + quad * 8];
            acc = __builtin_amdgcn_mfma_f32_16x16x32_bf16(a, sb[ch & 3], acc, 0, 0, 0);
            if (ch + 4 < 32) sb[ch & 3] = *(const bf16x8*)(bp + (ch + 4) * 32);
        }
        float bs = ffn_b2[col];
#pragma unroll
        for (int r = 0; r < 4; ++r) {
            int row = quad * 4 + r, grow = grow0 + row;
            float mk = (float)get_mask(nmask, fm, grow);
            out[(size_t)grow * DIMM + col] = x1s[row][col] + (acc[r] + bs) * mk;
        }
    }
}

// ---------------- launch ----------------
extern "C" void kernel_launch(void* const* d_in, const int* in_sizes, int n_in,
                              void* d_out, int out_size, void* d_ws, size_t ws_size,
                              hipStream_t stream) {
    const float* x       = (const float*)d_in[0];
    const int*   etypes  = (const int*)d_in[1];
    const void*  nmask   = d_in[2];
    const float* qkv_w   = (const float*)d_in[3];
    const float* qkv_b   = (const float*)d_in[4];
    const float* proj_w  = (const float*)d_in[5];
    const float* proj_b  = (const float*)d_in[6];
    const float* table   = (const float*)d_in[7];
    const float* ln1_g   = (const float*)d_in[8];
    const float* ln1_b   = (const float*)d_in[9];
    const float* ln2_g   = (const float*)d_in[10];
    const float* ln2_b   = (const float*)d_in[11];
    const float* ffn_w1  = (const float*)d_in[12];
    const float* ffn_b1  = (const float*)d_in[13];
    const float* ffn_w2  = (const float*)d_in[14];
    const float* ffn_b2  = (const float*)d_in[15];
    float* out = (float*)d_out;
    float* ws  = (float*)d_ws;

    float* lpart = ws;                               // 131,072 f (512 KB)
    unsigned short* ub = (unsigned short*)(ws + 131072);
    unsigned short* h_ln   = ub;                     // 1,048,576 us
    unsigned short* qkvh   = ub + 1048576;           // 2,097,152
    unsigned short* vT     = ub + 3145728;           // 1,048,576
    unsigned short* OpH    = ub + 4194304;           // 4,194,304 (4 splits)
    unsigned short* qkvT   = ub + 8388608;           // 196,608
    unsigned short* projT  = ub + 8585216;           // 65,536
    unsigned short* f1T    = ub + 8650752;           // 262,144
    unsigned short* f2T    = ub + 8912896;           // 262,144
    unsigned char* emaskP  = (unsigned char*)(ub + 9175040);  // 4,194,304 B
    unsigned short* qidx   = ub + 11272192;          // 4,096 us
    int* nv                = (int*)(ub + 11276288);  // 2 ints

    scan_kernel<<<dim3(BB), dim3(256), 0, stream>>>(nmask, nv, qidx, lpart);
    prep_kernel<<<dim3(2752), dim3(256), 0, stream>>>(
        qkv_w, proj_w, ffn_w1, ffn_w2, qkvT, projT, f1T, f2T,
        x, ln1_g, ln1_b, h_ln, etypes, nmask, emaskP, nv, qidx);
    gemm_qkv_mfma<<<dim3(12, 64), dim3(256), 0, stream>>>(h_ln, qkvT, qkv_b, qkvh, vT);
    attn_mfma<<<dim3(HEADS, NB/64, BB*4), dim3(256), 0, stream>>>(
        qkvh, vT, emaskP, table, nv, qidx, OpH, lpart);
    megaback<<<dim3(ROWS/16), dim3(1024), 0, stream>>>(
        OpH, lpart, projT, proj_b, x, nmask, ln2_g, ln2_b,
        f1T, ffn_b1, f2T, ffn_b2, out);
}

// Round 13
// 203.517 us; speedup vs baseline: 1.7919x; 1.0794x over previous
//
#include <hip/hip_runtime.h>
#include <math.h>

#define DIMM 256
#define HEADS 8
#define NB 2048
#define BB 2
#define ROWS (BB*NB)   // 4096

typedef __attribute__((ext_vector_type(8))) short bf16x8;
typedef __attribute__((ext_vector_type(4))) short bf16x4;
typedef __attribute__((ext_vector_type(4))) float f32x4;

__device__ inline unsigned short f2bf(float f) {
    unsigned int u = __float_as_uint(f);
    u += 0x7FFFu + ((u >> 16) & 1u);           // RNE
    return (unsigned short)(u >> 16);
}
__device__ inline float bf2f(unsigned short u) {
    return __uint_as_float(((unsigned int)u) << 16);
}

__device__ inline int get_mask(const void* nm, int fmt, int idx) {
    if (fmt) return ((const unsigned char*)nm)[idx] != 0;
    return ((const int*)nm)[idx] != 0;
}

// ---------------- scan (blocks 0..BB-1) + masked-row copyout (blocks BB..) ----------
// Masked rows: reference gives out[row] == x[row] exactly (proj*0, ffn*0).
__global__ __launch_bounds__(256) void scan_copy_kernel(
    const void* __restrict__ nmask, int* __restrict__ nv,
    unsigned short* __restrict__ qidx,
    const float* __restrict__ x, float* __restrict__ out)
{
    __shared__ int fsh;
    __shared__ int cnt[256];
    __shared__ int base[256];
    int bid = blockIdx.x, t = threadIdx.x;
    if (t == 0) fsh = 0;
    __syncthreads();
    if (((const unsigned char*)nmask)[4 * t + 1] != 0) fsh = 1;
    __syncthreads();
    int fm = fsh;
    if (bid < BB) {
        int b = bid;
        int m[8]; int c = 0;
#pragma unroll
        for (int i = 0; i < 8; ++i) {
            m[i] = get_mask(nmask, fm, b * NB + t * 8 + i);
            c += m[i];
        }
        cnt[t] = c;
        __syncthreads();
        if (t == 0) {
            int acc = 0;
            for (int i = 0; i < 256; ++i) { base[i] = acc; acc += cnt[i]; }
            nv[b] = acc;
        }
        __syncthreads();
        int off = base[t];
#pragma unroll
        for (int i = 0; i < 8; ++i) {
            int row = t * 8 + i;
            if (m[i]) qidx[b * NB + off++] = (unsigned short)row;
        }
        __syncthreads();
        if (t == 0) {   // pad to multiple of 64 with last valid row (safe dup reads)
            int n = nv[b];
            unsigned short last = (n > 0) ? qidx[b * NB + n - 1] : (unsigned short)0;
            int padend = (n + 63) & ~63;
            for (int i = n; i < padend; ++i) qidx[b * NB + i] = last;
        }
    } else {
        int row = (bid - BB) * 8 + (t >> 5);
        if (!get_mask(nmask, fm, row)) {
            int c0 = (t & 31) * 8;
            float4 v0 = *(const float4*)&x[(size_t)row * DIMM + c0];
            float4 v1 = *(const float4*)&x[(size_t)row * DIMM + c0 + 4];
            *(float4*)&out[(size_t)row * DIMM + c0]     = v0;
            *(float4*)&out[(size_t)row * DIMM + c0 + 4] = v1;
        }
    }
}

// ---------------- LayerNorm body: read row xrow, write compact slot orow ----------
__device__ inline void ln8_body(const float* __restrict__ x, const float* __restrict__ g,
                                const float* __restrict__ bb, unsigned short* __restrict__ o,
                                int xrow, int orow, int lane32) {
    int c0 = lane32 * 8;
    float4 v0 = *(const float4*)&x[(size_t)xrow * DIMM + c0];
    float4 v1 = *(const float4*)&x[(size_t)xrow * DIMM + c0 + 4];
    float s  = v0.x + v0.y + v0.z + v0.w + v1.x + v1.y + v1.z + v1.w;
    float s2 = v0.x*v0.x + v0.y*v0.y + v0.z*v0.z + v0.w*v0.w
             + v1.x*v1.x + v1.y*v1.y + v1.z*v1.z + v1.w*v1.w;
#pragma unroll
    for (int off = 16; off >= 1; off >>= 1) {
        s  += __shfl_xor(s,  off);
        s2 += __shfl_xor(s2, off);
    }
    float mean = s * (1.0f / DIMM);
    float var  = s2 * (1.0f / DIMM) - mean * mean;
    float rstd = rsqrtf(var + 1e-5f);
    float4 g0 = *(const float4*)&g[c0],  g1 = *(const float4*)&g[c0 + 4];
    float4 b0 = *(const float4*)&bb[c0], b1 = *(const float4*)&bb[c0 + 4];
    ushort4 u0, u1;
    u0.x = f2bf((v0.x - mean) * rstd * g0.x + b0.x);
    u0.y = f2bf((v0.y - mean) * rstd * g0.y + b0.y);
    u0.z = f2bf((v0.z - mean) * rstd * g0.z + b0.z);
    u0.w = f2bf((v0.w - mean) * rstd * g0.w + b0.w);
    u1.x = f2bf((v1.x - mean) * rstd * g1.x + b1.x);
    u1.y = f2bf((v1.y - mean) * rstd * g1.y + b1.y);
    u1.z = f2bf((v1.z - mean) * rstd * g1.z + b1.z);
    u1.w = f2bf((v1.w - mean) * rstd * g1.w + b1.w);
    *(ushort4*)&o[(size_t)orow * DIMM + c0]     = u0;
    *(ushort4*)&o[(size_t)orow * DIMM + c0 + 4] = u1;
}

// ---------------- prep: w2bfT (0..191) + compact LN1 (192..703) + emaskP (704..2751) --
// emaskP (fully compact): per (b, qt16, kt) unit of 512B. Lane L holds int2 at L*8:
// nibble for [q slot = qt16*16 + (L&15)][key slot = kt*64 + t16*16 + (L>>4)*4 + r]
// in dword (t16>>1), bits ((t16&1)*16 + r*4). Code 0 = invalid; else etype+1.
__global__ __launch_bounds__(256) void prep_kernel(
    const float* __restrict__ w0, const float* __restrict__ w1,
    const float* __restrict__ w2, const float* __restrict__ w3,
    unsigned short* __restrict__ o0, unsigned short* __restrict__ o1,
    unsigned short* __restrict__ o2, unsigned short* __restrict__ o3,
    const float* __restrict__ x, const float* __restrict__ ln1_g,
    const float* __restrict__ ln1_b, unsigned short* __restrict__ h_ln,
    const int* __restrict__ etypes,
    unsigned char* __restrict__ emaskP,
    const int* __restrict__ nv, const unsigned short* __restrict__ qidx)
{
    __shared__ float tile[64][65];
    int bid = blockIdx.x, t = threadIdx.x;
    if (bid < 192) {
        const float* src; unsigned short* dst; int K, N, idx;
        if (bid < 48)       { src = w0; dst = o0; K = 256;  N = 768;  idx = bid; }
        else if (bid < 64)  { src = w1; dst = o1; K = 256;  N = 256;  idx = bid - 48; }
        else if (bid < 128) { src = w2; dst = o2; K = 256;  N = 1024; idx = bid - 64; }
        else                { src = w3; dst = o3; K = 1024; N = 256;  idx = bid - 128; }
        int ntiles = N >> 6;
        int k0 = (idx / ntiles) * 64, n0 = (idx % ntiles) * 64;
        int r = t >> 4, c4 = (t & 15) * 4;
#pragma unroll
        for (int i = 0; i < 4; ++i) {
            float4 v = *(const float4*)&src[(size_t)(k0 + r + i * 16) * N + n0 + c4];
            tile[r + i * 16][c4 + 0] = v.x;
            tile[r + i * 16][c4 + 1] = v.y;
            tile[r + i * 16][c4 + 2] = v.z;
            tile[r + i * 16][c4 + 3] = v.w;
        }
        __syncthreads();
#pragma unroll
        for (int i = 0; i < 4; ++i) {
            int n = n0 + r + i * 16;
            ushort4 u;
            u.x = f2bf(tile[c4 + 0][r + i * 16]);
            u.y = f2bf(tile[c4 + 1][r + i * 16]);
            u.z = f2bf(tile[c4 + 2][r + i * 16]);
            u.w = f2bf(tile[c4 + 3][r + i * 16]);
            *(ushort4*)&dst[(size_t)n * K + k0 + c4] = u;
        }
    } else if (bid < 704) {
        int slotg = (bid - 192) * 8 + (t >> 5);
        int b = slotg >> 11, sl = slotg & 2047;
        int nvp = (nv[b] + 63) & ~63;
        if (sl < nvp) {
            int row = qidx[b * NB + sl];
            ln8_body(x, ln1_g, ln1_b, h_ln, b * NB + row, slotg, t & 31);
        }
    } else {
        int unit = (bid - 704) * 4 + (t >> 6);
        int lane = t & 63, quad = lane >> 4, l15 = lane & 15;
        int b = unit >> 12;                 // 4096 units per batch
        int qt16 = (unit >> 5) & 127;
        int kt = unit & 31;
        int nvb = nv[b];
        int nvp = (nvb + 63) & ~63;
        if (qt16 * 16 >= nvb || kt * 64 >= nvp) return;
        int slot = qt16 * 16 + l15;
        int validq = slot < nvb;
        int qr = qidx[b * NB + slot];       // padded to mult-64, safe
        const int* erow = etypes + (size_t)(b * NB + qr) * NB;
        unsigned int dw[2] = {0u, 0u};
#pragma unroll
        for (int t16 = 0; t16 < 4; ++t16) {
#pragma unroll
            for (int r = 0; r < 4; ++r) {
                int ks = kt * 64 + t16 * 16 + quad * 4 + r;
                unsigned int code = 0u;
                if (validq && ks < nvb) {
                    int korig = qidx[b * NB + ks];
                    int et = erow[korig];
                    if ((et != 0) || (korig == qr)) code = (unsigned int)(et + 1);
                }
                dw[t16 >> 1] |= code << ((t16 & 1) * 16 + r * 4);
            }
        }
        int2 o = {(int)dw[0], (int)dw[1]};
        *(int2*)(emaskP + (size_t)unit * 512 + lane * 8) = o;
    }
}

// ---------------- compact qkv GEMM (64x64); q pre-scaled; per-batch grid -------------
__global__ __launch_bounds__(256) void gemm_qkv_mfma(
    const unsigned short* __restrict__ A, const unsigned short* __restrict__ Bt,
    const float* __restrict__ bias, const int* __restrict__ nv,
    unsigned short* __restrict__ qkvh, unsigned short* __restrict__ vT)
{
    const int K = 256;
    int t = threadIdx.x, w = t >> 6, l = t & 63;
    int l15 = l & 15, quad = l >> 4;
    int n0 = blockIdx.x * 64;
    int m0c = blockIdx.y * 64;
    int b = blockIdx.z;
    int nvp = (nv[b] + 63) & ~63;
    if (m0c >= nvp) return;
    const unsigned short* ap = A + (size_t)(b * NB + m0c + w * 16 + l15) * K + quad * 8;
    const unsigned short* bp = Bt + (size_t)(n0 + l15) * K + quad * 8;

    f32x4 acc[4];
#pragma unroll
    for (int c = 0; c < 4; ++c) acc[c] = (f32x4){0.f, 0.f, 0.f, 0.f};

    bf16x8 aA, bA[4], aB, bB[4];
    auto ld = [&](bf16x8& af, bf16x8 (&bf)[4], int k0) {
        af = *(const bf16x8*)(ap + k0);
#pragma unroll
        for (int c = 0; c < 4; ++c)
            bf[c] = *(const bf16x8*)(bp + (size_t)(c * 16) * K + k0);
    };
    auto pr = [&](const bf16x8& af, const bf16x8 (&bf)[4]) {
#pragma unroll
        for (int c = 0; c < 4; ++c)
            acc[c] = __builtin_amdgcn_mfma_f32_16x16x32_bf16(af, bf[c], acc[c], 0, 0, 0);
    };
    ld(aA, bA, 0);
    for (int k0 = 0; k0 < K; k0 += 64) {
        ld(aB, bB, k0 + 32);
        pr(aA, bA);
        if (k0 + 64 < K) ld(aA, bA, k0 + 64);
        pr(aB, bB);
    }

    if (n0 < 512) {
        float sc = (n0 < 256) ? 0.17677669529663689f : 1.0f;   // fold 1/sqrt(32) into q
#pragma unroll
        for (int r = 0; r < 4; ++r) {
            int slot = b * NB + m0c + w * 16 + quad * 4 + r;
#pragma unroll
            for (int c = 0; c < 4; ++c) {
                int col = n0 + c * 16 + l15;
                qkvh[(size_t)slot * 512 + col] = f2bf((acc[c][r] + bias[col]) * sc);
            }
        }
    } else {
        int n = m0c + w * 16 + quad * 4;
#pragma unroll
        for (int c = 0; c < 4; ++c) {
            int col = n0 + c * 16 + l15 - 512;
            int hidx = col >> 5, d = col & 31;
            float bs = bias[n0 + c * 16 + l15];
            ushort4 u;
            u.x = f2bf(acc[c][0] + bs);
            u.y = f2bf(acc[c][1] + bs);
            u.z = f2bf(acc[c][2] + bs);
            u.w = f2bf(acc[c][3] + bs);
            *(ushort4*)&vT[(size_t)((b * HEADS + hidx) * 32 + d) * NB + n] = u;
        }
    }
}

// ---------------- MFMA attention: fully compact (q AND k), S^T + b64 P + R6 PV -------
__global__ __launch_bounds__(256) void attn_mfma(
    const unsigned short* __restrict__ qkvh,  // compact [4096][512] bf16: q(scaled)|k
    const unsigned short* __restrict__ vT,    // compact [512][2048] bf16
    const unsigned char* __restrict__ emaskP, // 4-bit fully-compact codes
    const float* __restrict__ table,
    const int* __restrict__ nv,
    unsigned short* __restrict__ OpH, float* __restrict__ lpart)
{
    __shared__ unsigned short P[4][16][72];
    __shared__ float tab2m[16];

    int t = threadIdx.x;
    int w = t >> 6, l = t & 63;
    int l15 = l & 15, quad = l >> 4;
    int h = blockIdx.x;                       // fastest -> id%8 == h (XCD pin)
    int qt = blockIdx.y;
    int z = blockIdx.z, b = z >> 2, sp = z & 3;

    if (t < 16) tab2m[t] = (t >= 1 && t < 10) ? __expf(table[(t - 1) * 8 + h]) : 0.f;
    __syncthreads();                          // no barriers after this point

    int nvb = nv[b];
    int qt16 = qt * 4 + w;
    int q0c = qt16 * 16;
    if (q0c >= nvb) return;                   // compact-q skip

    int nkt = (nvb + 63) >> 6;                // key tiles
    int tps = (nkt + 3) >> 2;                 // tiles per split
    int kbase = sp * tps * 64;
    int kend = min(kbase + tps * 64, nkt * 64);

    bf16x8 bq = *(const bf16x8*)(qkvh + (size_t)(b * NB + q0c + l15) * 512 + h * 32 + quad * 8);

    const unsigned short* kp = qkvh + (size_t)(b * NB + l15) * 512 + 256 + h * 32 + quad * 8;
    const unsigned short* vp = vT + (size_t)((b * HEADS + h) * 32 + l15) * NB + quad * 8;
    const unsigned char* ep = emaskP + (size_t)((b * 128 + qt16) * 32) * 512 + l * 8;

    float lacc = 0.f;
    f32x4 O0 = {0.f, 0.f, 0.f, 0.f}, O1 = {0.f, 0.f, 0.f, 0.f};

    bf16x8 kA[4], kB[4];
    bf16x8 vA[2][2], vB[2][2];
    int2 eA, eB;

    auto loadtile = [&](bf16x8 (&kf)[4], bf16x8 (&vf)[2][2], int2& ef, int m0) {
#pragma unroll
        for (int t16 = 0; t16 < 4; ++t16)
            kf[t16] = *(const bf16x8*)(kp + (size_t)(m0 + t16 * 16) * 512);
#pragma unroll
        for (int ks = 0; ks < 2; ++ks) {
            vf[ks][0] = *(const bf16x8*)(vp + m0 + ks * 32);
            vf[ks][1] = *(const bf16x8*)(vp + 16 * NB + m0 + ks * 32);
        }
        ef = *(const int2*)(ep + (size_t)(m0 >> 6) * 512);
    };

    auto process = [&](const bf16x8 (&kf)[4], const bf16x8 (&vf)[2][2], const int2& ef) {
#pragma unroll
        for (int t16 = 0; t16 < 4; ++t16) {
            f32x4 zero = {0.f, 0.f, 0.f, 0.f};
            f32x4 sT = __builtin_amdgcn_mfma_f32_16x16x32_bf16(kf[t16], bq, zero, 0, 0, 0);
            unsigned int e = ((unsigned int)((t16 < 2) ? ef.x : ef.y)) >> ((t16 & 1) * 16);
            float p0 = __expf(sT[0]) * tab2m[e & 0xFu];
            float p1 = __expf(sT[1]) * tab2m[(e >> 4) & 0xFu];
            float p2 = __expf(sT[2]) * tab2m[(e >> 8) & 0xFu];
            float p3 = __expf(sT[3]) * tab2m[(e >> 12) & 0xFu];
            lacc += (p0 + p1) + (p2 + p3);
            bf16x4 pb;
            pb[0] = (short)f2bf(p0); pb[1] = (short)f2bf(p1);
            pb[2] = (short)f2bf(p2); pb[3] = (short)f2bf(p3);
            *(bf16x4*)&P[w][l15][t16 * 16 + quad * 4] = pb;
        }
#pragma unroll
        for (int ks = 0; ks < 2; ++ks) {
            bf16x8 pa = *(const bf16x8*)&P[w][l15][ks * 32 + quad * 8];
            O0 = __builtin_amdgcn_mfma_f32_16x16x32_bf16(pa, vf[ks][0], O0, 0, 0, 0);
            O1 = __builtin_amdgcn_mfma_f32_16x16x32_bf16(pa, vf[ks][1], O1, 0, 0, 0);
        }
    };

    if (kbase < kend) {
        loadtile(kA, vA, eA, kbase);
        for (int m0 = kbase; m0 < kend; m0 += 128) {
            int n1 = (m0 + 64 < kend) ? m0 + 64 : kbase;
            loadtile(kB, vB, eB, n1);
            process(kA, vA, eA);
            if (m0 + 128 < kend) loadtile(kA, vA, eA, m0 + 128);
            if (m0 + 64 < kend) process(kB, vB, eB);
        }
    }

    lacc += __shfl_xor(lacc, 16);
    lacc += __shfl_xor(lacc, 32);

    unsigned short* Ob = OpH + (size_t)sp * ROWS * DIMM;
#pragma unroll
    for (int r = 0; r < 4; ++r) {
        int slot = q0c + quad * 4 + r;
        if (slot < nvb) {
            Ob[(size_t)(b * NB + slot) * DIMM + h * 32 + l15]      = f2bf(O0[r]);
            Ob[(size_t)(b * NB + slot) * DIMM + h * 32 + 16 + l15] = f2bf(O1[r]);
        }
    }
    if (quad == 0 && q0c + l15 < nvb)
        lpart[(size_t)sp * ROWS * 8 + (size_t)(b * NB + q0c + l15) * 8 + h] = lacc;
}

// ---------------- megaback (compact): combine+proj+LN2+ffn1+gelu+ffn2, scatter out ----
__global__ __launch_bounds__(1024) void megaback(
    const unsigned short* __restrict__ OpH, const float* __restrict__ lpart,
    const unsigned short* __restrict__ projT, const float* __restrict__ proj_b,
    const float* __restrict__ x,
    const float* __restrict__ g2, const float* __restrict__ b2,
    const unsigned short* __restrict__ f1T, const float* __restrict__ ffn_b1,
    const unsigned short* __restrict__ f2T, const float* __restrict__ ffn_b2,
    const int* __restrict__ nv, const unsigned short* __restrict__ qidx,
    float* __restrict__ out)
{
    __shared__ float rinv_l[16][8];
    __shared__ float stats[16][2];
    __shared__ float redn[16][16][2];
    __shared__ unsigned short Astage[16][264];
    __shared__ float x1s[16][260];
    __shared__ unsigned short hstage[16][264];
    __shared__ unsigned short midstage[16][1032];

    int t = threadIdx.x;
    int w = t >> 6, l = t & 63;
    int l15 = l & 15, quad = l >> 4;
    int b = blockIdx.x >> 7;
    int s0 = (blockIdx.x & 127) * 16;
    int nvb = nv[b];
    if (s0 >= nvb) return;                    // block-uniform, before barriers
    int slot0 = b * NB + s0;

    if (t < 128) {
        int row = t >> 3, h = t & 7;
        float s = 0.f;
#pragma unroll
        for (int sp = 0; sp < 4; ++sp)
            s += lpart[(size_t)sp * ROWS * 8 + (size_t)(slot0 + row) * 8 + h];
        rinv_l[row][h] = (s > 0.f) ? 1.f / s : 0.f;
    }
    __syncthreads();

    {
        int row = t >> 6, col4 = (t & 63) * 4;
        float rinv = rinv_l[row][col4 >> 5];
        float o0 = 0.f, o1 = 0.f, o2 = 0.f, o3 = 0.f;
#pragma unroll
        for (int sp = 0; sp < 4; ++sp) {
            ushort4 u = *(const ushort4*)&OpH[(size_t)sp * ROWS * DIMM +
                                             (size_t)(slot0 + row) * DIMM + col4];
            o0 += bf2f(u.x); o1 += bf2f(u.y); o2 += bf2f(u.z); o3 += bf2f(u.w);
        }
        ushort4 u;
        u.x = f2bf(o0 * rinv); u.y = f2bf(o1 * rinv);
        u.z = f2bf(o2 * rinv); u.w = f2bf(o3 * rinv);
        *(ushort4*)&Astage[row][col4] = u;
    }
    __syncthreads();

    {
        int col = w * 16 + l15;
        f32x4 acc = (f32x4){0.f, 0.f, 0.f, 0.f};
        const unsigned short* bp = projT + (size_t)col * 256 + quad * 8;
        bf16x8 sb[4];
#pragma unroll
        for (int i = 0; i < 4; ++i) sb[i] = *(const bf16x8*)(bp + i * 32);
#pragma unroll
        for (int ch = 0; ch < 8; ++ch) {
            bf16x8 a = *(const bf16x8*)&Astage[l15][ch * 32 + quad * 8];
            acc = __builtin_amdgcn_mfma_f32_16x16x32_bf16(a, sb[ch & 3], acc, 0, 0, 0);
            if (ch + 4 < 8) sb[ch & 3] = *(const bf16x8*)(bp + (ch + 4) * 32);
        }
        float bs = proj_b[col];
#pragma unroll
        for (int r = 0; r < 4; ++r) {
            int row = quad * 4 + r;
            int grow = b * NB + qidx[(size_t)slot0 + row - (size_t)b * NB + b * NB];
            grow = b * NB + qidx[(size_t)(slot0 + row)];
            float v = (acc[r] + bs) + x[(size_t)grow * DIMM + col];   // mask==1 here
            x1s[row][col] = v;
            float s = v, s2 = v * v;
#pragma unroll
            for (int off = 1; off < 16; off <<= 1) {
                s += __shfl_xor(s, off); s2 += __shfl_xor(s2, off);
            }
            if (l15 == 0) { redn[row][w][0] = s; redn[row][w][1] = s2; }
        }
    }
    __syncthreads();
    if (t < 16) {
        float s = 0.f, s2 = 0.f;
#pragma unroll
        for (int ww = 0; ww < 16; ++ww) { s += redn[t][ww][0]; s2 += redn[t][ww][1]; }
        float mean = s * (1.f / DIMM);
        float var  = s2 * (1.f / DIMM) - mean * mean;
        stats[t][0] = mean; stats[t][1] = rsqrtf(var + 1e-5f);
    }
    __syncthreads();

    {
        int col = w * 16 + l15;
        float gv = g2[col], bv = b2[col];
#pragma unroll
        for (int r = 0; r < 4; ++r) {
            int row = quad * 4 + r;
            float hv = (x1s[row][col] - stats[row][0]) * stats[row][1] * gv + bv;
            hstage[row][col] = f2bf(hv);
        }
    }
    __syncthreads();

    {
        f32x4 acc[4];
#pragma unroll
        for (int c = 0; c < 4; ++c) acc[c] = (f32x4){0.f, 0.f, 0.f, 0.f};
        const unsigned short* bp = f1T + (size_t)(w * 64 + l15) * 256 + quad * 8;
        bf16x8 bA[4], bB[4];
#pragma unroll
        for (int c = 0; c < 4; ++c) bA[c] = *(const bf16x8*)(bp + (size_t)(c * 16) * 256);
#pragma unroll
        for (int ch = 0; ch < 8; ++ch) {
            bf16x8 a = *(const bf16x8*)&hstage[l15][ch * 32 + quad * 8];
            if (ch + 1 < 8) {
#pragma unroll
                for (int c = 0; c < 4; ++c)
                    bB[c] = *(const bf16x8*)(bp + (size_t)(c * 16) * 256 + (ch + 1) * 32);
            }
#pragma unroll
            for (int c = 0; c < 4; ++c)
                acc[c] = __builtin_amdgcn_mfma_f32_16x16x32_bf16(a, bA[c], acc[c], 0, 0, 0);
#pragma unroll
            for (int c = 0; c < 4; ++c) bA[c] = bB[c];
        }
#pragma unroll
        for (int c = 0; c < 4; ++c) {
            int col = w * 64 + c * 16 + l15;
            float bs = ffn_b1[col];
#pragma unroll
            for (int r = 0; r < 4; ++r) {
                float v = acc[c][r] + bs;
                float x2 = v * v;
                float p = v * fmaf(0.07135481f, x2, 1.5957691f);
                float e = __expf(p);
                float gl = v * (e / (e + 1.f));
                midstage[quad * 4 + r][col] = f2bf(gl);
            }
        }
    }
    __syncthreads();

    {
        int col = w * 16 + l15;
        f32x4 acc = (f32x4){0.f, 0.f, 0.f, 0.f};
        const unsigned short* bp = f2T + (size_t)col * 1024 + quad * 8;
        bf16x8 sb[4];
#pragma unroll
        for (int i = 0; i < 4; ++i) sb[i] = *(const bf16x8*)(bp + i * 32);
#pragma unroll
        for (int ch = 0; ch < 32; ++ch) {
            bf16x8 a = *(const bf16x8*)&midstage[l15][ch * 32 + quad * 8];
            acc = __builtin_amdgcn_mfma_f32_16x16x32_bf16(a, sb[ch & 3], acc, 0, 0, 0);
            if (ch + 4 < 32) sb[ch & 3] = *(const bf16x8*)(bp + (ch + 4) * 32);
        }
        float bs = ffn_b2[col];
#pragma unroll
        for (int r = 0; r < 4; ++r) {
            int row = quad * 4 + r;
            if (s0 + row < nvb) {
                int grow = b * NB + qidx[(size_t)(slot0 + row)];
                out[(size_t)grow * DIMM + col] = x1s[row][col] + (acc[r] + bs);
            }
        }
    }
}

// ---------------- launch ----------------
extern "C" void kernel_launch(void* const* d_in, const int* in_sizes, int n_in,
                              void* d_out, int out_size, void* d_ws, size_t ws_size,
                              hipStream_t stream) {
    const float* x       = (const float*)d_in[0];
    const int*   etypes  = (const int*)d_in[1];
    const void*  nmask   = d_in[2];
    const float* qkv_w   = (const float*)d_in[3];
    const float* qkv_b   = (const float*)d_in[4];
    const float* proj_w  = (const float*)d_in[5];
    const float* proj_b  = (const float*)d_in[6];
    const float* table   = (const float*)d_in[7];
    const float* ln1_g   = (const float*)d_in[8];
    const float* ln1_b   = (const float*)d_in[9];
    const float* ln2_g   = (const float*)d_in[10];
    const float* ln2_b   = (const float*)d_in[11];
    const float* ffn_w1  = (const float*)d_in[12];
    const float* ffn_b1  = (const float*)d_in[13];
    const float* ffn_w2  = (const float*)d_in[14];
    const float* ffn_b2  = (const float*)d_in[15];
    float* out = (float*)d_out;
    float* ws  = (float*)d_ws;

    float* lpart = ws;                               // 131,072 f (512 KB)
    unsigned short* ub = (unsigned short*)(ws + 131072);
    unsigned short* h_ln   = ub;                     // 1,048,576 us (compact)
    unsigned short* qkvh   = ub + 1048576;           // 2,097,152 (compact)
    unsigned short* vT     = ub + 3145728;           // 1,048,576 (compact)
    unsigned short* OpH    = ub + 4194304;           // 4,194,304 (compact, 4 splits)
    unsigned short* qkvT   = ub + 8388608;           // 196,608
    unsigned short* projT  = ub + 8585216;           // 65,536
    unsigned short* f1T    = ub + 8650752;           // 262,144
    unsigned short* f2T    = ub + 8912896;           // 262,144
    unsigned char* emaskP  = (unsigned char*)(ub + 9175040);  // 4,194,304 B
    unsigned short* qidx   = ub + 11272192;          // 4,096 us
    int* nv                = (int*)(ub + 11276288);  // 2 ints

    scan_copy_kernel<<<dim3(BB + ROWS/8), dim3(256), 0, stream>>>(nmask, nv, qidx, x, out);
    prep_kernel<<<dim3(2752), dim3(256), 0, stream>>>(
        qkv_w, proj_w, ffn_w1, ffn_w2, qkvT, projT, f1T, f2T,
        x, ln1_g, ln1_b, h_ln, etypes, emaskP, nv, qidx);
    gemm_qkv_mfma<<<dim3(12, 32, BB), dim3(256), 0, stream>>>(h_ln, qkvT, qkv_b, nv, qkvh, vT);
    attn_mfma<<<dim3(HEADS, NB/64, BB*4), dim3(256), 0, stream>>>(
        qkvh, vT, emaskP, table, nv, OpH, lpart);
    megaback<<<dim3(2 * 128), dim3(1024), 0, stream>>>(
        OpH, lpart, projT, proj_b, x, ln2_g, ln2_b,
        f1T, ffn_b1, f2T, ffn_b2, nv, qidx, out);
}